// Round 1
// baseline (229.572 us; speedup 1.0000x reference)
//
#include <hip/hip_runtime.h>
#include <hip/hip_bf16.h>
#include <stdint.h>

#define Bn 8192
#define Dk 512

typedef __attribute__((ext_vector_type(8))) short short8;
typedef __attribute__((ext_vector_type(4))) float f32x4;

// fp32 -> bf16 bits, round-to-nearest-even
__device__ __forceinline__ unsigned short f2bf(float f) {
  unsigned int u = __float_as_uint(f);
  u += 0x7FFFu + ((u >> 16) & 1u);
  return (unsigned short)(u >> 16);
}

// async global -> LDS, 16 bytes per lane (dest = wave-uniform base + lane*16)
__device__ __forceinline__ void gload_lds16(const unsigned short* g, unsigned short* l) {
  __builtin_amdgcn_global_load_lds(
      (const __attribute__((address_space(1))) void*)g,
      (__attribute__((address_space(3))) void*)l,
      16, 0, 0);
}

// ---------------------------------------------------------------------------
// Kernel 1: cast fp32 embeddings to bf16 (for MFMA) + exact fp32 row norms.
// One block (256 thr) per row; first 8192 blocks = text, next 8192 = image.
// ---------------------------------------------------------------------------
__global__ __launch_bounds__(256) void prep_kernel(
    const float* __restrict__ T, const float* __restrict__ M,
    unsigned short* __restrict__ Tb, unsigned short* __restrict__ Mb,
    float* __restrict__ tn, float* __restrict__ mn)
{
  const int bid = blockIdx.x;
  const int row = bid & (Bn - 1);
  const bool isM = bid >= Bn;
  const float* __restrict__ src = isM ? M : T;
  unsigned short* __restrict__ dst = isM ? Mb : Tb;
  const int tid = threadIdx.x;

  float2 v = reinterpret_cast<const float2*>(src + (size_t)row * Dk)[tid];
  float s = v.x * v.x + v.y * v.y;
  unsigned int packed = (unsigned int)f2bf(v.x) | ((unsigned int)f2bf(v.y) << 16);
  reinterpret_cast<unsigned int*>(dst + (size_t)row * Dk)[tid] = packed;

  #pragma unroll
  for (int off = 32; off >= 1; off >>= 1) s += __shfl_xor(s, off, 64);
  __shared__ float ws4[4];
  const int wave = tid >> 6, lane = tid & 63;
  if (lane == 0) ws4[wave] = s;
  __syncthreads();
  if (tid == 0) {
    float* nrm = isM ? mn : tn;
    nrm[row] = ws4[0] + ws4[1] + ws4[2] + ws4[3];
  }
}

// ---------------------------------------------------------------------------
// Kernel 2: 128x128-tile bf16 MFMA GEMM (dot = T . M^T) with fused epilogue:
//   sq = |t|^2 + |m|^2 - 2 dot ; sim = exp(-sqrt(sq)) ; accumulate per-row
//   numerator (same group) / denominator (diff group) via atomics.
// 4 waves (2x2), each computing a 64x64 sub-tile via 4x4 16x16x32 fragments.
// Double-buffered LDS staged with global_load_lds width=16.
// ---------------------------------------------------------------------------
__global__ __launch_bounds__(256, 2) void gemm_epi_kernel(
    const unsigned short* __restrict__ Tb, const unsigned short* __restrict__ Mb,
    const float* __restrict__ tn, const float* __restrict__ mn,
    const int* __restrict__ groups,
    float* __restrict__ num, float* __restrict__ den)
{
  __shared__ alignas(16) short As[2][128 * 32];
  __shared__ alignas(16) short Bs[2][128 * 32];

  const int tid = threadIdx.x;
  const int wave = tid >> 6;
  const int lane = tid & 63;
  const int brow = blockIdx.y * 128;
  const int bcol = blockIdx.x * 128;
  const int wr = wave >> 1;   // 0..1: which 64-row half
  const int wc = wave & 1;    // 0..1: which 64-col half

  f32x4 acc[4][4];
  #pragma unroll
  for (int m = 0; m < 4; ++m)
    #pragma unroll
    for (int n = 0; n < 4; ++n)
      acc[m][n] = f32x4{0.f, 0.f, 0.f, 0.f};

  // stage one 128x32 K-tile of A and B into LDS buffer `buf`
  auto stage = [&](int kt, int buf) {
    const int k0 = kt * 32;
    #pragma unroll
    for (int i = 0; i < 2; ++i) {
      const int cb = wave * 128 + i * 64;  // wave-uniform chunk base (16B chunks)
      const int c = cb + lane;             // this lane's chunk: 0..511
      const int row = c >> 2;              // 0..127
      const int kk = (c & 3) * 8;          // 0,8,16,24
      gload_lds16(Tb + (size_t)(brow + row) * Dk + k0 + kk,
                  (unsigned short*)&As[buf][cb * 8]);
      gload_lds16(Mb + (size_t)(bcol + row) * Dk + k0 + kk,
                  (unsigned short*)&Bs[buf][cb * 8]);
    }
  };

  stage(0, 0);

  const int lhi = lane >> 4;   // 0..3  (k-block / acc row group)
  const int llo = lane & 15;   // 0..15 (fragment row/col)

  for (int kt = 0; kt < Dk / 32; ++kt) {
    __syncthreads();                       // stage(kt) done; prior reads done
    if (kt + 1 < Dk / 32) stage(kt + 1, (kt + 1) & 1);
    const int buf = kt & 1;
    short8 af[4], bf[4];
    #pragma unroll
    for (int m = 0; m < 4; ++m)
      af[m] = *reinterpret_cast<const short8*>(
          &As[buf][(wr * 64 + m * 16 + llo) * 32 + lhi * 8]);
    #pragma unroll
    for (int n = 0; n < 4; ++n)
      bf[n] = *reinterpret_cast<const short8*>(
          &Bs[buf][(wc * 64 + n * 16 + llo) * 32 + lhi * 8]);
    #pragma unroll
    for (int m = 0; m < 4; ++m)
      #pragma unroll
      for (int n = 0; n < 4; ++n)
        acc[m][n] = __builtin_amdgcn_mfma_f32_16x16x32_bf16(af[m], bf[n], acc[m][n], 0, 0, 0);
  }

  // ---- fused epilogue ----
  const int row0 = brow + wr * 64;
  const int col0 = bcol + wc * 64;

  float mnv[4];
  int gcol[4];
  #pragma unroll
  for (int n = 0; n < 4; ++n) {
    const int c = col0 + n * 16 + llo;
    mnv[n] = mn[c];
    gcol[n] = groups[c];
  }

  #pragma unroll
  for (int m = 0; m < 4; ++m) {
    const int rbase = row0 + m * 16 + lhi * 4;
    #pragma unroll
    for (int r = 0; r < 4; ++r) {
      const int row = rbase + r;
      const float tnv = tn[row];
      const int grow = groups[row];
      float nv = 0.f, dv = 0.f;
      #pragma unroll
      for (int n = 0; n < 4; ++n) {
        float sq = tnv + mnv[n] - 2.0f * acc[m][n][r];
        sq = fmaxf(sq, 0.f);
        const float dist = __builtin_amdgcn_sqrtf(sq);
        const float sim = __builtin_amdgcn_exp2f(-1.4426950408889634f * dist);
        if (grow == gcol[n]) nv += sim; else dv += sim;
      }
      // reduce the 16 columns held by this 16-lane group (same row)
      #pragma unroll
      for (int off = 1; off < 16; off <<= 1) {
        nv += __shfl_xor(nv, off, 64);
        dv += __shfl_xor(dv, off, 64);
      }
      if (llo == 0) {
        atomicAdd(&num[row], nv);
        atomicAdd(&den[row], dv);
      }
    }
  }
}

// ---------------------------------------------------------------------------
// Kernel 3: loss = sum_i -log(num_i/den_i) [valid] / B
// ---------------------------------------------------------------------------
__global__ __launch_bounds__(256) void finalize_kernel(
    const float* __restrict__ num, const float* __restrict__ den,
    float* __restrict__ out)
{
  const int tid = threadIdx.x;
  float s = 0.f;
  for (int i = tid; i < Bn; i += 256) {
    const float nu = num[i], de = den[i];
    if (nu > 0.f && de > 0.f)
      s += (__builtin_amdgcn_logf(de) - __builtin_amdgcn_logf(nu)) * 0.69314718055994531f;
  }
  #pragma unroll
  for (int off = 32; off >= 1; off >>= 1) s += __shfl_xor(s, off, 64);
  __shared__ float ws4[4];
  const int wave = tid >> 6, lane = tid & 63;
  if (lane == 0) ws4[wave] = s;
  __syncthreads();
  if (tid == 0) out[0] = (ws4[0] + ws4[1] + ws4[2] + ws4[3]) / (float)Bn;
}

// ---------------------------------------------------------------------------
extern "C" void kernel_launch(void* const* d_in, const int* in_sizes, int n_in,
                              void* d_out, int out_size, void* d_ws, size_t ws_size,
                              hipStream_t stream) {
  const float* T = (const float*)d_in[0];
  const float* M = (const float*)d_in[1];
  const int* groups = (const int*)d_in[2];

  char* ws = (char*)d_ws;
  unsigned short* Tb = (unsigned short*)ws;                          // 8 MB bf16 text
  unsigned short* Mb = (unsigned short*)(ws + (size_t)Bn * Dk * 2);  // 8 MB bf16 image
  float* tn  = (float*)(ws + (size_t)Bn * Dk * 4);                   // 32 KB
  float* mn  = tn + Bn;                                              // 32 KB
  float* num = mn + Bn;                                              // 32 KB
  float* den = num + Bn;                                             // 32 KB

  hipMemsetAsync(num, 0, 2 * Bn * sizeof(float), stream);
  prep_kernel<<<2 * Bn, 256, 0, stream>>>(T, M, Tb, Mb, tn, mn);
  gemm_epi_kernel<<<dim3(64, 64), 256, 0, stream>>>(Tb, Mb, tn, mn, groups, num, den);
  finalize_kernel<<<1, 256, 0, stream>>>(num, den, (float*)d_out);
}

// Round 2
// 217.302 us; speedup vs baseline: 1.0565x; 1.0565x over previous
//
#include <hip/hip_runtime.h>
#include <hip/hip_bf16.h>
#include <stdint.h>

#define Bn 8192
#define Dk 512

typedef __attribute__((ext_vector_type(8))) short short8;
typedef __attribute__((ext_vector_type(4))) float f32x4;

// fp32 -> bf16 bits, round-to-nearest-even
__device__ __forceinline__ unsigned short f2bf(float f) {
  unsigned int u = __float_as_uint(f);
  u += 0x7FFFu + ((u >> 16) & 1u);
  return (unsigned short)(u >> 16);
}

// async global -> LDS, 16 bytes per lane (dest = wave-uniform base + lane*16)
__device__ __forceinline__ void gload_lds16(const unsigned short* g, unsigned short* l) {
  __builtin_amdgcn_global_load_lds(
      (const __attribute__((address_space(1))) void*)g,
      (__attribute__((address_space(3))) void*)l,
      16, 0, 0);
}

// ---------------------------------------------------------------------------
// Kernel 1: cast fp32 embeddings to bf16 (for MFMA) + exact fp32 row norms.
// One block (256 thr) per row; first 8192 blocks = text, next 8192 = image.
// ---------------------------------------------------------------------------
__global__ __launch_bounds__(256) void prep_kernel(
    const float* __restrict__ T, const float* __restrict__ M,
    unsigned short* __restrict__ Tb, unsigned short* __restrict__ Mb,
    float* __restrict__ tn, float* __restrict__ mn)
{
  const int bid = blockIdx.x;
  const int row = bid & (Bn - 1);
  const bool isM = bid >= Bn;
  const float* __restrict__ src = isM ? M : T;
  unsigned short* __restrict__ dst = isM ? Mb : Tb;
  const int tid = threadIdx.x;

  float2 v = reinterpret_cast<const float2*>(src + (size_t)row * Dk)[tid];
  float s = v.x * v.x + v.y * v.y;
  unsigned int packed = (unsigned int)f2bf(v.x) | ((unsigned int)f2bf(v.y) << 16);
  reinterpret_cast<unsigned int*>(dst + (size_t)row * Dk)[tid] = packed;

  #pragma unroll
  for (int off = 32; off >= 1; off >>= 1) s += __shfl_xor(s, off, 64);
  __shared__ float ws4[4];
  const int wave = tid >> 6, lane = tid & 63;
  if (lane == 0) ws4[wave] = s;
  __syncthreads();
  if (tid == 0) {
    float* nrm = isM ? mn : tn;
    nrm[row] = ws4[0] + ws4[1] + ws4[2] + ws4[3];
  }
}

// ---------------------------------------------------------------------------
// Kernel 2: 128x128-tile bf16 MFMA GEMM (dot = T . M^T) with fused epilogue.
// LDS tile [128 rows][4 slots of 16B]; slot s holds k-chunk s ^ ((row>>1)&3)
// (XOR swizzle, applied on the pre-swizzled GLOBAL source so the linear
// global_load_lds dest works — rule #21). Read side applies the same XOR:
// 16 consecutive rows then cover all 8 bank-groups -> 2-way (free).
// ---------------------------------------------------------------------------
__global__ __launch_bounds__(256, 3) void gemm_epi_kernel(
    const unsigned short* __restrict__ Tb, const unsigned short* __restrict__ Mb,
    const float* __restrict__ tn, const float* __restrict__ mn,
    const int* __restrict__ groups,
    float* __restrict__ num, float* __restrict__ den)
{
  __shared__ alignas(16) short As[2][128 * 32];
  __shared__ alignas(16) short Bs[2][128 * 32];

  const int tid = threadIdx.x;
  const int wave = tid >> 6;
  const int lane = tid & 63;
  const int brow = blockIdx.y * 128;
  const int bcol = blockIdx.x * 128;
  const int wr = wave >> 1;   // 0..1: which 64-row half
  const int wc = wave & 1;    // 0..1: which 64-col half

  f32x4 acc[4][4];
  #pragma unroll
  for (int m = 0; m < 4; ++m)
    #pragma unroll
    for (int n = 0; n < 4; ++n)
      acc[m][n] = f32x4{0.f, 0.f, 0.f, 0.f};

  // staging geometry (kt-independent): lane's chunk + swizzled source k-chunk
  const int cb0 = wave * 128;            // wave-uniform chunk base, i=0
  const int cb1 = wave * 128 + 64;       // i=1
  const int c0 = cb0 + lane, c1 = cb1 + lane;
  const int row_0 = c0 >> 2, row_1 = c1 >> 2;
  const int kc0 = (c0 & 3) ^ ((row_0 >> 1) & 3);   // pre-swizzled source chunk
  const int kc1 = (c1 & 3) ^ ((row_1 >> 1) & 3);
  const size_t ga0 = (size_t)(brow + row_0) * Dk + kc0 * 8;
  const size_t ga1 = (size_t)(brow + row_1) * Dk + kc1 * 8;
  const size_t gb0 = (size_t)(bcol + row_0) * Dk + kc0 * 8;
  const size_t gb1 = (size_t)(bcol + row_1) * Dk + kc1 * 8;

  auto stage = [&](int kt, int buf) {
    const int k0 = kt * 32;
    gload_lds16(Tb + ga0 + k0, (unsigned short*)&As[buf][cb0 * 8]);
    gload_lds16(Mb + gb0 + k0, (unsigned short*)&Bs[buf][cb0 * 8]);
    gload_lds16(Tb + ga1 + k0, (unsigned short*)&As[buf][cb1 * 8]);
    gload_lds16(Mb + gb1 + k0, (unsigned short*)&Bs[buf][cb1 * 8]);
  };

  stage(0, 0);

  const int lhi = lane >> 4;   // 0..3  (k-chunk within K=32 step)
  const int llo = lane & 15;   // 0..15 (fragment row/col)

  // hoisted swizzled read offsets (in shorts), kt-independent
  int aoff[4], boff[4];
  #pragma unroll
  for (int m = 0; m < 4; ++m) {
    const int r = wr * 64 + m * 16 + llo;
    aoff[m] = r * 32 + (lhi ^ ((r >> 1) & 3)) * 8;
  }
  #pragma unroll
  for (int n = 0; n < 4; ++n) {
    const int r = wc * 64 + n * 16 + llo;
    boff[n] = r * 32 + (lhi ^ ((r >> 1) & 3)) * 8;
  }

  for (int kt = 0; kt < Dk / 32; ++kt) {
    __syncthreads();                       // stage(kt) landed; prior reads done
    if (kt + 1 < Dk / 32) stage(kt + 1, (kt + 1) & 1);
    const int buf = kt & 1;
    short8 af[4], bf[4];
    #pragma unroll
    for (int m = 0; m < 4; ++m)
      af[m] = *reinterpret_cast<const short8*>(&As[buf][aoff[m]]);
    #pragma unroll
    for (int n = 0; n < 4; ++n)
      bf[n] = *reinterpret_cast<const short8*>(&Bs[buf][boff[n]]);
    #pragma unroll
    for (int m = 0; m < 4; ++m)
      #pragma unroll
      for (int n = 0; n < 4; ++n)
        acc[m][n] = __builtin_amdgcn_mfma_f32_16x16x32_bf16(af[m], bf[n], acc[m][n], 0, 0, 0);
  }

  // ---- fused epilogue ----
  const int row0 = brow + wr * 64;
  const int col0 = bcol + wc * 64;

  float mnv[4];
  int gcol[4];
  #pragma unroll
  for (int n = 0; n < 4; ++n) {
    const int c = col0 + n * 16 + llo;
    mnv[n] = mn[c];
    gcol[n] = groups[c];
  }

  #pragma unroll
  for (int m = 0; m < 4; ++m) {
    const int rbase = row0 + m * 16 + lhi * 4;
    #pragma unroll
    for (int r = 0; r < 4; ++r) {
      const int row = rbase + r;
      const float tnv = tn[row];
      const int grow = groups[row];
      float nv = 0.f, dv = 0.f;
      #pragma unroll
      for (int n = 0; n < 4; ++n) {
        float sq = tnv + mnv[n] - 2.0f * acc[m][n][r];
        sq = fmaxf(sq, 0.f);
        const float dist = __builtin_amdgcn_sqrtf(sq);
        const float sim = __builtin_amdgcn_exp2f(-1.4426950408889634f * dist);
        if (grow == gcol[n]) nv += sim; else dv += sim;
      }
      // reduce the 16 columns held by this 16-lane group (same row)
      #pragma unroll
      for (int off = 1; off < 16; off <<= 1) {
        nv += __shfl_xor(nv, off, 64);
        dv += __shfl_xor(dv, off, 64);
      }
      if (llo == 0) {
        atomicAdd(&num[row], nv);
        atomicAdd(&den[row], dv);
      }
    }
  }
}

// ---------------------------------------------------------------------------
// Kernel 3: loss = sum_i -log(num_i/den_i) [valid] / B
// ---------------------------------------------------------------------------
__global__ __launch_bounds__(256) void finalize_kernel(
    const float* __restrict__ num, const float* __restrict__ den,
    float* __restrict__ out)
{
  const int tid = threadIdx.x;
  float s = 0.f;
  for (int i = tid; i < Bn; i += 256) {
    const float nu = num[i], de = den[i];
    if (nu > 0.f && de > 0.f)
      s += (__builtin_amdgcn_logf(de) - __builtin_amdgcn_logf(nu)) * 0.69314718055994531f;
  }
  #pragma unroll
  for (int off = 32; off >= 1; off >>= 1) s += __shfl_xor(s, off, 64);
  __shared__ float ws4[4];
  const int wave = tid >> 6, lane = tid & 63;
  if (lane == 0) ws4[wave] = s;
  __syncthreads();
  if (tid == 0) out[0] = (ws4[0] + ws4[1] + ws4[2] + ws4[3]) / (float)Bn;
}

// ---------------------------------------------------------------------------
extern "C" void kernel_launch(void* const* d_in, const int* in_sizes, int n_in,
                              void* d_out, int out_size, void* d_ws, size_t ws_size,
                              hipStream_t stream) {
  const float* T = (const float*)d_in[0];
  const float* M = (const float*)d_in[1];
  const int* groups = (const int*)d_in[2];

  char* ws = (char*)d_ws;
  unsigned short* Tb = (unsigned short*)ws;                          // 8 MB bf16 text
  unsigned short* Mb = (unsigned short*)(ws + (size_t)Bn * Dk * 2);  // 8 MB bf16 image
  float* tn  = (float*)(ws + (size_t)Bn * Dk * 4);                   // 32 KB
  float* mn  = tn + Bn;                                              // 32 KB
  float* num = mn + Bn;                                              // 32 KB
  float* den = num + Bn;                                             // 32 KB

  hipMemsetAsync(num, 0, 2 * Bn * sizeof(float), stream);
  prep_kernel<<<2 * Bn, 256, 0, stream>>>(T, M, Tb, Mb, tn, mn);
  gemm_epi_kernel<<<dim3(64, 64), 256, 0, stream>>>(Tb, Mb, tn, mn, groups, num, den);
  finalize_kernel<<<1, 256, 0, stream>>>(num, den, (float*)d_out);
}

// Round 3
// 114.404 us; speedup vs baseline: 2.0067x; 1.8994x over previous
//
#include <hip/hip_runtime.h>
#include <hip/hip_bf16.h>
#include <stdint.h>

#define Bn 8192
#define Dk 512

typedef __attribute__((ext_vector_type(8))) short short8;
typedef __attribute__((ext_vector_type(4))) float f32x4;

// fp32 -> bf16 bits, round-to-nearest-even
__device__ __forceinline__ unsigned short f2bf(float f) {
  unsigned int u = __float_as_uint(f);
  u += 0x7FFFu + ((u >> 16) & 1u);
  return (unsigned short)(u >> 16);
}

// async global -> LDS, 16 bytes per lane (dest = wave-uniform base + lane*16)
__device__ __forceinline__ void gload_lds16(const unsigned short* g, unsigned short* l) {
  __builtin_amdgcn_global_load_lds(
      (const __attribute__((address_space(1))) void*)g,
      (__attribute__((address_space(3))) void*)l,
      16, 0, 0);
}

// ---------------------------------------------------------------------------
// Kernel 1: cast fp32 embeddings to bf16 (for MFMA) + exact fp32 row norms.
// ---------------------------------------------------------------------------
__global__ __launch_bounds__(256) void prep_kernel(
    const float* __restrict__ T, const float* __restrict__ M,
    unsigned short* __restrict__ Tb, unsigned short* __restrict__ Mb,
    float* __restrict__ tn, float* __restrict__ mn)
{
  const int bid = blockIdx.x;
  const int row = bid & (Bn - 1);
  const bool isM = bid >= Bn;
  const float* __restrict__ src = isM ? M : T;
  unsigned short* __restrict__ dst = isM ? Mb : Tb;
  const int tid = threadIdx.x;

  float2 v = reinterpret_cast<const float2*>(src + (size_t)row * Dk)[tid];
  float s = v.x * v.x + v.y * v.y;
  unsigned int packed = (unsigned int)f2bf(v.x) | ((unsigned int)f2bf(v.y) << 16);
  reinterpret_cast<unsigned int*>(dst + (size_t)row * Dk)[tid] = packed;

  #pragma unroll
  for (int off = 32; off >= 1; off >>= 1) s += __shfl_xor(s, off, 64);
  __shared__ float ws4[4];
  const int wave = tid >> 6, lane = tid & 63;
  if (lane == 0) ws4[wave] = s;
  __syncthreads();
  if (tid == 0) {
    float* nrm = isM ? mn : tn;
    nrm[row] = ws4[0] + ws4[1] + ws4[2] + ws4[3];
  }
}

// ---------------------------------------------------------------------------
// Kernel 2: 128x128-tile bf16 MFMA GEMM with fused, ATOMIC-FREE epilogue.
// Operands SWAPPED in the MFMA (image frag as A, text frag as B) so the
// output col index (lane&15) is the TEXT row -> the per-text-row reduction
// over image indices is register-local (16 values per lane), then an 8-way
// LDS combine (red[] aliased onto dead As[0]). One coalesced float2 partial
// store per block into part[bx][text_row]. No atomics, no memset needed.
// ---------------------------------------------------------------------------
__global__ __launch_bounds__(256, 3) void gemm_epi_kernel(
    const unsigned short* __restrict__ Tb, const unsigned short* __restrict__ Mb,
    const float* __restrict__ tn, const float* __restrict__ mn,
    const int* __restrict__ groups,
    float2* __restrict__ part)
{
  __shared__ alignas(16) short As[2][128 * 32];
  __shared__ alignas(16) short Bs[2][128 * 32];
  __shared__ float2 tg_s[128];   // (text norm, bitcast group)
  __shared__ float2 mg_s[128];   // (image norm, bitcast group)

  const int tid = threadIdx.x;
  const int wave = tid >> 6;
  const int lane = tid & 63;

  // bijective XCD-chunked swizzle (nwg=4096, divisible by 8)
  const int bid = blockIdx.x;
  const int swz = (bid & 7) * 512 + (bid >> 3);
  const int by = swz >> 6;          // text panel
  const int bx = swz & 63;          // image panel
  const int brow = by * 128;
  const int bcol = bx * 128;
  const int wr = wave >> 1;         // text half of the wave tile
  const int wc = wave & 1;          // image half

  if (tid < 128) {
    tg_s[tid] = make_float2(tn[brow + tid], __uint_as_float((unsigned)groups[brow + tid]));
  } else {
    const int t = tid - 128;
    mg_s[t] = make_float2(mn[bcol + t], __uint_as_float((unsigned)groups[bcol + t]));
  }

  f32x4 acc[4][4];   // acc[it][jt]: it = image frag, jt = text frag
  #pragma unroll
  for (int it = 0; it < 4; ++it)
    #pragma unroll
    for (int jt = 0; jt < 4; ++jt)
      acc[it][jt] = f32x4{0.f, 0.f, 0.f, 0.f};

  // staging geometry (kt-independent); XOR-swizzled global source (rule #21)
  const int cb0 = wave * 128;
  const int cb1 = wave * 128 + 64;
  const int c0 = cb0 + lane, c1 = cb1 + lane;
  const int row_0 = c0 >> 2, row_1 = c1 >> 2;
  const int kc0 = (c0 & 3) ^ ((row_0 >> 1) & 3);
  const int kc1 = (c1 & 3) ^ ((row_1 >> 1) & 3);
  const size_t ga0 = (size_t)(brow + row_0) * Dk + kc0 * 8;
  const size_t ga1 = (size_t)(brow + row_1) * Dk + kc1 * 8;
  const size_t gb0 = (size_t)(bcol + row_0) * Dk + kc0 * 8;
  const size_t gb1 = (size_t)(bcol + row_1) * Dk + kc1 * 8;

  auto stage = [&](int kt, int buf) {
    const int k0 = kt * 32;
    gload_lds16(Tb + ga0 + k0, (unsigned short*)&As[buf][cb0 * 8]);
    gload_lds16(Mb + gb0 + k0, (unsigned short*)&Bs[buf][cb0 * 8]);
    gload_lds16(Tb + ga1 + k0, (unsigned short*)&As[buf][cb1 * 8]);
    gload_lds16(Mb + gb1 + k0, (unsigned short*)&Bs[buf][cb1 * 8]);
  };

  stage(0, 0);

  const int lhi = lane >> 4;   // k-chunk on load side; image sub-row on output
  const int llo = lane & 15;   // fragment row/col; text index on output

  // hoisted swizzled read offsets (in shorts)
  int aoff[4], boff[4];
  #pragma unroll
  for (int jt = 0; jt < 4; ++jt) {
    const int r = wr * 64 + jt * 16 + llo;
    aoff[jt] = r * 32 + (lhi ^ ((r >> 1) & 3)) * 8;
  }
  #pragma unroll
  for (int it = 0; it < 4; ++it) {
    const int r = wc * 64 + it * 16 + llo;
    boff[it] = r * 32 + (lhi ^ ((r >> 1) & 3)) * 8;
  }

  for (int kt = 0; kt < Dk / 32; ++kt) {
    __syncthreads();                       // stage(kt) landed; prior reads done
    if (kt + 1 < Dk / 32) stage(kt + 1, (kt + 1) & 1);
    const int buf = kt & 1;
    short8 af[4], bf[4];
    #pragma unroll
    for (int jt = 0; jt < 4; ++jt)
      af[jt] = *reinterpret_cast<const short8*>(&As[buf][aoff[jt]]);
    #pragma unroll
    for (int it = 0; it < 4; ++it)
      bf[it] = *reinterpret_cast<const short8*>(&Bs[buf][boff[it]]);
    #pragma unroll
    for (int it = 0; it < 4; ++it)
      #pragma unroll
      for (int jt = 0; jt < 4; ++jt)
        acc[it][jt] = __builtin_amdgcn_mfma_f32_16x16x32_bf16(bf[it], af[jt], acc[it][jt], 0, 0, 0);
  }

  // ---- fused epilogue (no atomics) ----
  // acc[it][jt][r] on lane (llo,lhi) = dot(image[bcol+wc*64+it*16+lhi*4+r],
  //                                        text [brow+wr*64+jt*16+llo])
  float2* red = reinterpret_cast<float2*>(&As[0][0]);   // 8 KB, As[0] is dead

  #pragma unroll
  for (int jt = 0; jt < 4; ++jt) {
    const int tl = wr * 64 + jt * 16 + llo;
    const float2 tg = tg_s[tl];
    const unsigned gt = __float_as_uint(tg.y);
    float nv = 0.f, dv = 0.f;
    #pragma unroll
    for (int it = 0; it < 4; ++it) {
      #pragma unroll
      for (int r = 0; r < 4; ++r) {
        const float2 mg = mg_s[wc * 64 + it * 16 + lhi * 4 + r];
        const float sq = fmaxf(tg.x + mg.x - 2.0f * acc[it][jt][r], 0.f);
        const float sim = __builtin_amdgcn_exp2f(-1.4426950408889634f *
                                                 __builtin_amdgcn_sqrtf(sq));
        if (gt == __float_as_uint(mg.y)) nv += sim; else dv += sim;
      }
    }
    red[(wc * 4 + lhi) * 128 + tl] = make_float2(nv, dv);
  }
  __syncthreads();
  if (tid < 128) {
    float nv = 0.f, dv = 0.f;
    #pragma unroll
    for (int s = 0; s < 8; ++s) {
      const float2 v = red[s * 128 + tid];
      nv += v.x; dv += v.y;
    }
    part[(size_t)bx * Bn + brow + tid] = make_float2(nv, dv);
  }
}

// ---------------------------------------------------------------------------
// Kernel 3a: per-row sum over the 64 image-panel partials + loss term;
// block-level partial sums. Kernel 3b: final 32-value reduce.
// ---------------------------------------------------------------------------
__global__ __launch_bounds__(256) void finalize1_kernel(
    const float2* __restrict__ part, float* __restrict__ bsum)
{
  const int i = blockIdx.x * 256 + threadIdx.x;
  float nv = 0.f, dv = 0.f;
  #pragma unroll 8
  for (int p = 0; p < 64; ++p) {
    const float2 v = part[(size_t)p * Bn + i];
    nv += v.x; dv += v.y;
  }
  float li = (nv > 0.f && dv > 0.f)
      ? (__builtin_amdgcn_logf(dv) - __builtin_amdgcn_logf(nv)) * 0.69314718055994531f
      : 0.f;
  #pragma unroll
  for (int off = 32; off >= 1; off >>= 1) li += __shfl_xor(li, off, 64);
  __shared__ float ws4[4];
  if ((threadIdx.x & 63) == 0) ws4[threadIdx.x >> 6] = li;
  __syncthreads();
  if (threadIdx.x == 0) bsum[blockIdx.x] = ws4[0] + ws4[1] + ws4[2] + ws4[3];
}

__global__ void finalize2_kernel(const float* __restrict__ bsum, float* __restrict__ out)
{
  float s = (threadIdx.x < 32) ? bsum[threadIdx.x] : 0.f;
  #pragma unroll
  for (int off = 32; off >= 1; off >>= 1) s += __shfl_xor(s, off, 64);
  if (threadIdx.x == 0) out[0] = s / (float)Bn;
}

// ---------------------------------------------------------------------------
extern "C" void kernel_launch(void* const* d_in, const int* in_sizes, int n_in,
                              void* d_out, int out_size, void* d_ws, size_t ws_size,
                              hipStream_t stream) {
  const float* T = (const float*)d_in[0];
  const float* M = (const float*)d_in[1];
  const int* groups = (const int*)d_in[2];

  char* ws = (char*)d_ws;
  unsigned short* Tb = (unsigned short*)ws;                          // 8 MB
  unsigned short* Mb = (unsigned short*)(ws + (size_t)Bn * Dk * 2);  // 8 MB
  float* tn  = (float*)(ws + (size_t)Bn * Dk * 4);                   // 32 KB
  float* mn  = tn + Bn;                                              // 32 KB
  float2* part = (float2*)(mn + Bn);                                 // 4 MB (64 x 8192)
  float* bsum = (float*)(part + (size_t)64 * Bn);                    // 128 B

  prep_kernel<<<2 * Bn, 256, 0, stream>>>(T, M, Tb, Mb, tn, mn);
  gemm_epi_kernel<<<4096, 256, 0, stream>>>(Tb, Mb, tn, mn, groups, part);
  finalize1_kernel<<<Bn / 256, 256, 0, stream>>>(part, bsum);
  finalize2_kernel<<<1, 64, 0, stream>>>(bsum, (float*)d_out);
}

// Round 4
// 100.699 us; speedup vs baseline: 2.2798x; 1.1361x over previous
//
#include <hip/hip_runtime.h>
#include <hip/hip_bf16.h>
#include <stdint.h>

#define Bn 8192
#define Dk 512

typedef __attribute__((ext_vector_type(8))) short short8;
typedef __attribute__((ext_vector_type(4))) float f32x4;

// fp32 -> bf16 bits, round-to-nearest-even
__device__ __forceinline__ unsigned short f2bf(float f) {
  unsigned int u = __float_as_uint(f);
  u += 0x7FFFu + ((u >> 16) & 1u);
  return (unsigned short)(u >> 16);
}

// async global -> LDS, 16 bytes per lane (dest = wave-uniform base + lane*16)
__device__ __forceinline__ void gload_lds16(const unsigned short* g, const short* l) {
  __builtin_amdgcn_global_load_lds(
      (const __attribute__((address_space(1))) void*)g,
      (__attribute__((address_space(3))) void*)l,
      16, 0, 0);
}

// ---------------------------------------------------------------------------
// Kernel 1: cast fp32 embeddings to bf16 (for MFMA) + exact fp32 row norms.
// ---------------------------------------------------------------------------
__global__ __launch_bounds__(256) void prep_kernel(
    const float* __restrict__ T, const float* __restrict__ M,
    unsigned short* __restrict__ Tb, unsigned short* __restrict__ Mb,
    float* __restrict__ tn, float* __restrict__ mn)
{
  const int bid = blockIdx.x;
  const int row = bid & (Bn - 1);
  const bool isM = bid >= Bn;
  const float* __restrict__ src = isM ? M : T;
  unsigned short* __restrict__ dst = isM ? Mb : Tb;
  const int tid = threadIdx.x;

  float2 v = reinterpret_cast<const float2*>(src + (size_t)row * Dk)[tid];
  float s = v.x * v.x + v.y * v.y;
  unsigned int packed = (unsigned int)f2bf(v.x) | ((unsigned int)f2bf(v.y) << 16);
  reinterpret_cast<unsigned int*>(dst + (size_t)row * Dk)[tid] = packed;

  #pragma unroll
  for (int off = 32; off >= 1; off >>= 1) s += __shfl_xor(s, off, 64);
  __shared__ float ws4[4];
  const int wave = tid >> 6, lane = tid & 63;
  if (lane == 0) ws4[wave] = s;
  __syncthreads();
  if (tid == 0) {
    float* nrm = isM ? mn : tn;
    nrm[row] = ws4[0] + ws4[1] + ws4[2] + ws4[3];
  }
}

// ---------------------------------------------------------------------------
// Kernel 2: 256x256-tile bf16 MFMA GEMM, BK=32, 4-deep LDS ring, counted
// vmcnt pipeline (stage 3 K-tiles ahead, vmcnt(12) steady state, never 0),
// 8 waves (2 image x 4 text), fused atomic-free epilogue (same as round 3).
// Ring-slot safety: overwrite of buf b (tile kt+3, issued in iter kt) is
// separated from the last reads of buf b (tile kt-1, iter kt-1) by the
// collective bar2(kt-1) which follows every wave's lgkmcnt(0).
// ---------------------------------------------------------------------------
__global__ __launch_bounds__(512, 2) void gemm_epi_kernel(
    const unsigned short* __restrict__ Tb, const unsigned short* __restrict__ Mb,
    const float* __restrict__ tn, const float* __restrict__ mn,
    const int* __restrict__ groups,
    float2* __restrict__ part)
{
  extern __shared__ char smem[];
  short* As = (short*)smem;                    // text tiles: 4 bufs x 256x32 bf16
  short* Bs = As + 4 * 8192;                   // image tiles: 4 bufs
  float2* tg_s = (float2*)(Bs + 4 * 8192);     // 256 (text norm, group bits)
  float2* mg_s = tg_s + 256;                   // 256 (image norm, group bits)

  const int tid = threadIdx.x;
  const int wave = tid >> 6;
  const int lane = tid & 63;
  const int llo = lane & 15, lhi = lane >> 4;

  // XCD-compact swizzle: 1024 blocks = 8 XCDs x (4 by x 32 bx), B-panel-major
  const int bid = blockIdx.x;
  const int xcd = bid & 7, lidx = bid >> 3;
  const int by = xcd * 4 + (lidx & 3);
  const int bx = lidx >> 2;
  const int brow = by * 256;   // text rows
  const int bcol = bx * 256;   // image rows

  const int ir = wave >> 2;    // image half: rows ir*128 .. +128
  const int tc = wave & 3;     // text quarter: cols tc*64 .. +64

  if (tid < 256) {
    tg_s[tid] = make_float2(tn[brow + tid], __uint_as_float((unsigned)groups[brow + tid]));
  } else {
    const int t = tid - 256;
    mg_s[t] = make_float2(mn[bcol + t], __uint_as_float((unsigned)groups[bcol + t]));
  }

  // staging geometry: K-tile = 256 rows x 32 bf16 = 1024 chunks of 16B;
  // 512 threads -> 2 issues per operand. Pre-swizzled global source (rule #21).
  int ldsoff[2];
  size_t gsrcT[2], gsrcM[2];
  #pragma unroll
  for (int i = 0; i < 2; ++i) {
    const int c = i * 512 + tid;
    const int row = c >> 2;
    const int sc = (c & 3) ^ ((row >> 1) & 3);
    gsrcT[i] = (size_t)(brow + row) * Dk + sc * 8;
    gsrcM[i] = (size_t)(bcol + row) * Dk + sc * 8;
    ldsoff[i] = (i * 512 + wave * 64) * 8;     // wave-uniform chunk base (shorts)
  }

  auto stage = [&](int kt, int buf) {
    const int k0 = kt * 32;
    #pragma unroll
    for (int i = 0; i < 2; ++i) {
      gload_lds16(Tb + gsrcT[i] + k0, As + buf * 8192 + ldsoff[i]);
      gload_lds16(Mb + gsrcM[i] + k0, Bs + buf * 8192 + ldsoff[i]);
    }
  };

  // fragment read offsets (XOR-swizzled, kt-independent; row stride 32 shorts)
  int toff[4], moff[8];
  #pragma unroll
  for (int jt = 0; jt < 4; ++jt) {
    const int r = tc * 64 + jt * 16 + llo;
    toff[jt] = r * 32 + (lhi ^ ((r >> 1) & 3)) * 8;
  }
  #pragma unroll
  for (int it = 0; it < 8; ++it) {
    const int r = ir * 128 + it * 16 + llo;
    moff[it] = r * 32 + (lhi ^ ((r >> 1) & 3)) * 8;
  }

  f32x4 acc[8][4];
  #pragma unroll
  for (int it = 0; it < 8; ++it)
    #pragma unroll
    for (int jt = 0; jt < 4; ++jt)
      acc[it][jt] = f32x4{0.f, 0.f, 0.f, 0.f};

  stage(0, 0); stage(1, 1); stage(2, 2);
  int kt = 0;

#define STEP(BUF, DO_STAGE, VMC)                                               \
  do {                                                                         \
    if (DO_STAGE) stage(kt + 3, ((BUF) + 3) & 3);                              \
    asm volatile("s_waitcnt vmcnt(" #VMC ")" ::: "memory");                    \
    __builtin_amdgcn_s_barrier();                                              \
    asm volatile("" ::: "memory");                                             \
    short8 tf[4], mf[8];                                                       \
    _Pragma("unroll")                                                          \
    for (int jt = 0; jt < 4; ++jt)                                             \
      tf[jt] = *reinterpret_cast<const short8*>(&As[(BUF) * 8192 + toff[jt]]); \
    _Pragma("unroll")                                                          \
    for (int it = 0; it < 8; ++it)                                             \
      mf[it] = *reinterpret_cast<const short8*>(&Bs[(BUF) * 8192 + moff[it]]); \
    asm volatile("s_waitcnt lgkmcnt(0)" ::: "memory");                         \
    __builtin_amdgcn_s_barrier();                                              \
    asm volatile("" ::: "memory");                                             \
    __builtin_amdgcn_s_setprio(1);                                             \
    _Pragma("unroll")                                                          \
    for (int it = 0; it < 8; ++it)                                             \
      _Pragma("unroll")                                                        \
      for (int jt = 0; jt < 4; ++jt)                                           \
        acc[it][jt] = __builtin_amdgcn_mfma_f32_16x16x32_bf16(                 \
            mf[it], tf[jt], acc[it][jt], 0, 0, 0);                             \
    __builtin_amdgcn_s_setprio(0);                                             \
    ++kt;                                                                      \
  } while (0)

  #pragma unroll 1
  for (int ko = 0; ko < 3; ++ko) {
    STEP(0, true, 12); STEP(1, true, 12); STEP(2, true, 12); STEP(3, true, 12);
  }
  STEP(0, true, 12);     // kt=12: stages tile 15 (last)
  STEP(1, false, 8);     // kt=13
  STEP(2, false, 4);     // kt=14
  STEP(3, false, 0);     // kt=15
#undef STEP

  // ---- fused epilogue (no atomics) ----
  // acc[it][jt][r] on lane (llo,lhi) = dot(image[bcol+ir*128+it*16+lhi*4+r],
  //                                        text [brow+tc*64+jt*16+llo])
  float2* red = reinterpret_cast<float2*>(As);   // 16 KB alias on buf0 (dead)

  #pragma unroll
  for (int jt = 0; jt < 4; ++jt) {
    const int tl = tc * 64 + jt * 16 + llo;
    const float2 tg = tg_s[tl];
    const unsigned gt = __float_as_uint(tg.y);
    float nv = 0.f, dv = 0.f;
    #pragma unroll
    for (int it = 0; it < 8; ++it) {
      #pragma unroll
      for (int r = 0; r < 4; ++r) {
        const float2 mg = mg_s[ir * 128 + it * 16 + lhi * 4 + r];
        const float sq = fmaxf(tg.x + mg.x - 2.0f * acc[it][jt][r], 0.f);
        const float sim = __builtin_amdgcn_exp2f(-1.4426950408889634f *
                                                 __builtin_amdgcn_sqrtf(sq));
        if (gt == __float_as_uint(mg.y)) nv += sim; else dv += sim;
      }
    }
    red[(ir * 4 + lhi) * 256 + tl] = make_float2(nv, dv);
  }
  __syncthreads();
  if (tid < 256) {
    float nv = 0.f, dv = 0.f;
    #pragma unroll
    for (int s = 0; s < 8; ++s) {
      const float2 v = red[s * 256 + tid];
      nv += v.x; dv += v.y;
    }
    part[(size_t)bx * Bn + brow + tid] = make_float2(nv, dv);
  }
}

// ---------------------------------------------------------------------------
// Kernel 3a: per-row sum over 32 image-panel partials + loss term -> block sums.
// Kernel 3b: final reduce of 32 block sums.
// ---------------------------------------------------------------------------
__global__ __launch_bounds__(256) void finalize1_kernel(
    const float2* __restrict__ part, float* __restrict__ bsum)
{
  const int i = blockIdx.x * 256 + threadIdx.x;
  float nv = 0.f, dv = 0.f;
  #pragma unroll 8
  for (int p = 0; p < 32; ++p) {
    const float2 v = part[(size_t)p * Bn + i];
    nv += v.x; dv += v.y;
  }
  float li = (nv > 0.f && dv > 0.f)
      ? (__builtin_amdgcn_logf(dv) - __builtin_amdgcn_logf(nv)) * 0.69314718055994531f
      : 0.f;
  #pragma unroll
  for (int off = 32; off >= 1; off >>= 1) li += __shfl_xor(li, off, 64);
  __shared__ float ws4[4];
  if ((threadIdx.x & 63) == 0) ws4[threadIdx.x >> 6] = li;
  __syncthreads();
  if (threadIdx.x == 0) bsum[blockIdx.x] = ws4[0] + ws4[1] + ws4[2] + ws4[3];
}

__global__ void finalize2_kernel(const float* __restrict__ bsum, float* __restrict__ out)
{
  float s = (threadIdx.x < 32) ? bsum[threadIdx.x] : 0.f;
  #pragma unroll
  for (int off = 32; off >= 1; off >>= 1) s += __shfl_xor(s, off, 64);
  if (threadIdx.x == 0) out[0] = s / (float)Bn;
}

// ---------------------------------------------------------------------------
extern "C" void kernel_launch(void* const* d_in, const int* in_sizes, int n_in,
                              void* d_out, int out_size, void* d_ws, size_t ws_size,
                              hipStream_t stream) {
  const float* T = (const float*)d_in[0];
  const float* M = (const float*)d_in[1];
  const int* groups = (const int*)d_in[2];

  char* ws = (char*)d_ws;
  unsigned short* Tb = (unsigned short*)ws;                          // 8 MB
  unsigned short* Mb = (unsigned short*)(ws + (size_t)Bn * Dk * 2);  // 8 MB
  float* tn  = (float*)(ws + (size_t)Bn * Dk * 4);                   // 32 KB
  float* mn  = tn + Bn;                                              // 32 KB
  float2* part = (float2*)(mn + Bn);                                 // 2 MB (32 x 8192)
  float* bsum = (float*)(part + (size_t)32 * Bn);                    // 128 B

  const int smem_bytes = 4 * 8192 * 2 * 2 + 512 * 8;   // 128 KB tiles + 4 KB norms
  hipFuncSetAttribute((const void*)gemm_epi_kernel,
                      hipFuncAttributeMaxDynamicSharedMemorySize, smem_bytes);

  prep_kernel<<<2 * Bn, 256, 0, stream>>>(T, M, Tb, Mb, tn, mn);
  gemm_epi_kernel<<<1024, 512, smem_bytes, stream>>>(Tb, Mb, tn, mn, groups, part);
  finalize1_kernel<<<Bn / 256, 256, 0, stream>>>(part, bsum);
  finalize2_kernel<<<1, 64, 0, stream>>>(bsum, (float*)d_out);
}

// Round 5
// 97.156 us; speedup vs baseline: 2.3629x; 1.0365x over previous
//
#include <hip/hip_runtime.h>
#include <hip/hip_bf16.h>
#include <stdint.h>

#define Bn 8192
#define Dk 512

typedef __attribute__((ext_vector_type(8))) short short8;
typedef __attribute__((ext_vector_type(4))) float f32x4;

// fp32 -> bf16 bits, round-to-nearest-even
__device__ __forceinline__ unsigned short f2bf(float f) {
  unsigned int u = __float_as_uint(f);
  u += 0x7FFFu + ((u >> 16) & 1u);
  return (unsigned short)(u >> 16);
}

// async global -> LDS, 16 bytes per lane (dest = wave-uniform base + lane*16)
__device__ __forceinline__ void gload_lds16(const unsigned short* g, const short* l) {
  __builtin_amdgcn_global_load_lds(
      (const __attribute__((address_space(1))) void*)g,
      (__attribute__((address_space(3))) void*)l,
      16, 0, 0);
}

// ---------------------------------------------------------------------------
// Kernel 1: cast fp32 embeddings to bf16 (for MFMA) + exact fp32 row norms.
// ---------------------------------------------------------------------------
__global__ __launch_bounds__(256) void prep_kernel(
    const float* __restrict__ T, const float* __restrict__ M,
    unsigned short* __restrict__ Tb, unsigned short* __restrict__ Mb,
    float* __restrict__ tn, float* __restrict__ mn)
{
  const int bid = blockIdx.x;
  const int row = bid & (Bn - 1);
  const bool isM = bid >= Bn;
  const float* __restrict__ src = isM ? M : T;
  unsigned short* __restrict__ dst = isM ? Mb : Tb;
  const int tid = threadIdx.x;

  float2 v = reinterpret_cast<const float2*>(src + (size_t)row * Dk)[tid];
  float s = v.x * v.x + v.y * v.y;
  unsigned int packed = (unsigned int)f2bf(v.x) | ((unsigned int)f2bf(v.y) << 16);
  reinterpret_cast<unsigned int*>(dst + (size_t)row * Dk)[tid] = packed;

  #pragma unroll
  for (int off = 32; off >= 1; off >>= 1) s += __shfl_xor(s, off, 64);
  __shared__ float ws4[4];
  const int wave = tid >> 6, lane = tid & 63;
  if (lane == 0) ws4[wave] = s;
  __syncthreads();
  if (tid == 0) {
    float* nrm = isM ? mn : tn;
    nrm[row] = ws4[0] + ws4[1] + ws4[2] + ws4[3];
  }
}

// ---------------------------------------------------------------------------
// Kernel 2: 256x256-tile bf16 MFMA GEMM, BK=32, 4-deep LDS ring, prefetch
// depth 2, SINGLE barrier per K-step placed BEFORE the lgkm wait:
//   stage(kt+2) -> vmcnt(8) -> s_barrier -> 12x ds_read -> lgkmcnt(0)
//   -> setprio(1) 32 MFMA setprio(0)
// Waves desync after the barrier so one wave's MFMA overlaps another's
// ds_read latency (m201 pattern). Ring safety: stage(kt+2) clobbers
// buf[kt-2]; every wave's reads of tile kt-2 completed (its own lgkmcnt(0))
// before it reached the iter-(kt-1) barrier, and all waves passed that
// barrier before any wave issues stage(kt+2) in iter kt.
// vmcnt(8): after stage(kt+2), own outstanding loads = tiles kt+1,kt+2 (8)
// plus possibly tile kt; waiting to 8 retires tile kt (in-order, m135).
// ---------------------------------------------------------------------------
__global__ __launch_bounds__(512, 2) void gemm_epi_kernel(
    const unsigned short* __restrict__ Tb, const unsigned short* __restrict__ Mb,
    const float* __restrict__ tn, const float* __restrict__ mn,
    const int* __restrict__ groups,
    float2* __restrict__ part)
{
  extern __shared__ char smem[];
  short* As = (short*)smem;                    // text tiles: 4 bufs x 256x32 bf16
  short* Bs = As + 4 * 8192;                   // image tiles: 4 bufs
  float2* tg_s = (float2*)(Bs + 4 * 8192);     // 256 (text norm, group bits)
  float2* mg_s = tg_s + 256;                   // 256 (image norm, group bits)

  const int tid = threadIdx.x;
  const int wave = tid >> 6;
  const int lane = tid & 63;
  const int llo = lane & 15, lhi = lane >> 4;

  // XCD-compact swizzle: 1024 blocks = 8 XCDs x (4 by x 32 bx), B-panel-major
  const int bid = blockIdx.x;
  const int xcd = bid & 7, lidx = bid >> 3;
  const int by = xcd * 4 + (lidx & 3);
  const int bx = lidx >> 2;
  const int brow = by * 256;   // text rows
  const int bcol = bx * 256;   // image rows

  const int ir = wave >> 2;    // image half: rows ir*128 .. +128
  const int tc = wave & 3;     // text quarter: cols tc*64 .. +64

  if (tid < 256) {
    tg_s[tid] = make_float2(tn[brow + tid], __uint_as_float((unsigned)groups[brow + tid]));
  } else {
    const int t = tid - 256;
    mg_s[t] = make_float2(mn[bcol + t], __uint_as_float((unsigned)groups[bcol + t]));
  }

  // staging geometry: K-tile = 256 rows x 32 bf16 = 1024 chunks of 16B;
  // 512 threads -> 2 issues per operand. Pre-swizzled global source (rule #21).
  int ldsoff[2];
  size_t gsrcT[2], gsrcM[2];
  #pragma unroll
  for (int i = 0; i < 2; ++i) {
    const int c = i * 512 + tid;
    const int row = c >> 2;
    const int sc = (c & 3) ^ ((row >> 1) & 3);
    gsrcT[i] = (size_t)(brow + row) * Dk + sc * 8;
    gsrcM[i] = (size_t)(bcol + row) * Dk + sc * 8;
    ldsoff[i] = (i * 512 + wave * 64) * 8;     // wave-uniform chunk base (shorts)
  }

  auto stage = [&](int kt, int buf) {
    const int k0 = kt * 32;
    #pragma unroll
    for (int i = 0; i < 2; ++i) {
      gload_lds16(Tb + gsrcT[i] + k0, As + buf * 8192 + ldsoff[i]);
      gload_lds16(Mb + gsrcM[i] + k0, Bs + buf * 8192 + ldsoff[i]);
    }
  };

  // fragment read offsets (XOR-swizzled, kt-independent; row stride 32 shorts)
  int toff[4], moff[8];
  #pragma unroll
  for (int jt = 0; jt < 4; ++jt) {
    const int r = tc * 64 + jt * 16 + llo;
    toff[jt] = r * 32 + (lhi ^ ((r >> 1) & 3)) * 8;
  }
  #pragma unroll
  for (int it = 0; it < 8; ++it) {
    const int r = ir * 128 + it * 16 + llo;
    moff[it] = r * 32 + (lhi ^ ((r >> 1) & 3)) * 8;
  }

  f32x4 acc[8][4];
  #pragma unroll
  for (int it = 0; it < 8; ++it)
    #pragma unroll
    for (int jt = 0; jt < 4; ++jt)
      acc[it][jt] = f32x4{0.f, 0.f, 0.f, 0.f};

  stage(0, 0); stage(1, 1);
  int kt = 0;

#define STEP(BUF, DO_STAGE, VMC)                                               \
  do {                                                                         \
    if (DO_STAGE) stage(kt + 2, ((BUF) + 2) & 3);                              \
    asm volatile("s_waitcnt vmcnt(" #VMC ")" ::: "memory");                    \
    __builtin_amdgcn_s_barrier();                                              \
    asm volatile("" ::: "memory");                                             \
    short8 tf[4], mf[8];                                                       \
    _Pragma("unroll")                                                          \
    for (int jt = 0; jt < 4; ++jt)                                             \
      tf[jt] = *reinterpret_cast<const short8*>(&As[(BUF) * 8192 + toff[jt]]); \
    _Pragma("unroll")                                                          \
    for (int it = 0; it < 8; ++it)                                             \
      mf[it] = *reinterpret_cast<const short8*>(&Bs[(BUF) * 8192 + moff[it]]); \
    asm volatile("s_waitcnt lgkmcnt(0)" ::: "memory");                         \
    __builtin_amdgcn_s_setprio(1);                                             \
    _Pragma("unroll")                                                          \
    for (int it = 0; it < 8; ++it)                                             \
      _Pragma("unroll")                                                        \
      for (int jt = 0; jt < 4; ++jt)                                           \
        acc[it][jt] = __builtin_amdgcn_mfma_f32_16x16x32_bf16(                 \
            mf[it], tf[jt], acc[it][jt], 0, 0, 0);                             \
    __builtin_amdgcn_s_setprio(0);                                             \
    ++kt;                                                                      \
  } while (0)

  #pragma unroll 1
  for (int ko = 0; ko < 3; ++ko) {
    STEP(0, true, 8); STEP(1, true, 8); STEP(2, true, 8); STEP(3, true, 8);
  }
  STEP(0, true, 8);      // kt=12: stages tile 14 -> buf 2
  STEP(1, true, 8);      // kt=13: stages tile 15 -> buf 3 (last)
  STEP(2, false, 4);     // kt=14: tiles 14,15 outstanding -> wait to 4
  STEP(3, false, 0);     // kt=15: drain
#undef STEP

  // ---- fused epilogue (no atomics) ----
  // acc[it][jt][r] on lane (llo,lhi) = dot(image[bcol+ir*128+it*16+lhi*4+r],
  //                                        text [brow+tc*64+jt*16+llo])
  // red aliases As buf0 (tile 12; every wave's reads of it finished >=2
  // barriers ago). Last K-step reads come from buf3 — no overlap.
  float2* red = reinterpret_cast<float2*>(As);   // 16 KB alias

  #pragma unroll
  for (int jt = 0; jt < 4; ++jt) {
    const int tl = tc * 64 + jt * 16 + llo;
    const float2 tg = tg_s[tl];
    const unsigned gt = __float_as_uint(tg.y);
    float nv = 0.f, dv = 0.f;
    #pragma unroll
    for (int it = 0; it < 8; ++it) {
      #pragma unroll
      for (int r = 0; r < 4; ++r) {
        const float2 mg = mg_s[ir * 128 + it * 16 + lhi * 4 + r];
        const float sq = fmaxf(tg.x + mg.x - 2.0f * acc[it][jt][r], 0.f);
        const float sim = __builtin_amdgcn_exp2f(-1.4426950408889634f *
                                                 __builtin_amdgcn_sqrtf(sq));
        if (gt == __float_as_uint(mg.y)) nv += sim; else dv += sim;
      }
    }
    red[(ir * 4 + lhi) * 256 + tl] = make_float2(nv, dv);
  }
  __syncthreads();
  if (tid < 256) {
    float nv = 0.f, dv = 0.f;
    #pragma unroll
    for (int s = 0; s < 8; ++s) {
      const float2 v = red[s * 256 + tid];
      nv += v.x; dv += v.y;
    }
    part[(size_t)bx * Bn + brow + tid] = make_float2(nv, dv);
  }
}

// ---------------------------------------------------------------------------
// Kernel 3a: per-row sum over 32 image-panel partials + loss term -> block sums.
// Kernel 3b: final reduce of 32 block sums.
// ---------------------------------------------------------------------------
__global__ __launch_bounds__(256) void finalize1_kernel(
    const float2* __restrict__ part, float* __restrict__ bsum)
{
  const int i = blockIdx.x * 256 + threadIdx.x;
  float nv = 0.f, dv = 0.f;
  #pragma unroll 8
  for (int p = 0; p < 32; ++p) {
    const float2 v = part[(size_t)p * Bn + i];
    nv += v.x; dv += v.y;
  }
  float li = (nv > 0.f && dv > 0.f)
      ? (__builtin_amdgcn_logf(dv) - __builtin_amdgcn_logf(nv)) * 0.69314718055994531f
      : 0.f;
  #pragma unroll
  for (int off = 32; off >= 1; off >>= 1) li += __shfl_xor(li, off, 64);
  __shared__ float ws4[4];
  if ((threadIdx.x & 63) == 0) ws4[threadIdx.x >> 6] = li;
  __syncthreads();
  if (threadIdx.x == 0) bsum[blockIdx.x] = ws4[0] + ws4[1] + ws4[2] + ws4[3];
}

__global__ void finalize2_kernel(const float* __restrict__ bsum, float* __restrict__ out)
{
  float s = (threadIdx.x < 32) ? bsum[threadIdx.x] : 0.f;
  #pragma unroll
  for (int off = 32; off >= 1; off >>= 1) s += __shfl_xor(s, off, 64);
  if (threadIdx.x == 0) out[0] = s / (float)Bn;
}

// ---------------------------------------------------------------------------
extern "C" void kernel_launch(void* const* d_in, const int* in_sizes, int n_in,
                              void* d_out, int out_size, void* d_ws, size_t ws_size,
                              hipStream_t stream) {
  const float* T = (const float*)d_in[0];
  const float* M = (const float*)d_in[1];
  const int* groups = (const int*)d_in[2];

  char* ws = (char*)d_ws;
  unsigned short* Tb = (unsigned short*)ws;                          // 8 MB
  unsigned short* Mb = (unsigned short*)(ws + (size_t)Bn * Dk * 2);  // 8 MB
  float* tn  = (float*)(ws + (size_t)Bn * Dk * 4);                   // 32 KB
  float* mn  = tn + Bn;                                              // 32 KB
  float2* part = (float2*)(mn + Bn);                                 // 2 MB (32 x 8192)
  float* bsum = (float*)(part + (size_t)32 * Bn);                    // 128 B

  const int smem_bytes = 4 * 8192 * 2 * 2 + 512 * 8;   // 128 KB tiles + 4 KB norms
  hipFuncSetAttribute((const void*)gemm_epi_kernel,
                      hipFuncAttributeMaxDynamicSharedMemorySize, smem_bytes);

  prep_kernel<<<2 * Bn, 256, 0, stream>>>(T, M, Tb, Mb, tn, mn);
  gemm_epi_kernel<<<1024, 512, smem_bytes, stream>>>(Tb, Mb, tn, mn, groups, part);
  finalize1_kernel<<<Bn / 256, 256, 0, stream>>>(part, bsum);
  finalize2_kernel<<<1, 64, 0, stream>>>(bsum, (float*)d_out);
}